// Round 9
// baseline (411.843 us; speedup 1.0000x reference)
//
#include <hip/hip_runtime.h>
#include <hip/hip_fp16.h>

#define TPB 256
#define CAP 8192           // slack entries per 256-node bucket (avg fill ~4082)
#define CAPSH 13           // log2(CAP)

// Buckets: 256 nodes each (dst>>8). N=50000 -> nb=196 (must be <=256).
// Bucket b owns pairs[b*CAP..) and csr[b*CAP..) -> no cross-bucket scan.
// meta[v] = { (offset<<10) | deg, bitcast(dis) }: one 8-B load per node.
// Layer kernels: 64 nodes/block, 16 nodes/WAVE (4 per 16-lane group) so the
// mm's ds_read_b128 of W is amortized over 16 nodes (was 4) -> LDS-pipe time
// per layer ~23us -> ~8us.

__device__ __forceinline__ int ld_idx(const void* p, long long i, int is64) {
    return is64 ? (int)((const long long*)p)[i] : ((const int*)p)[i];
}

// Single block: edge-dtype detection + gcur[b] = b*CAP.
__global__ void init_all(const unsigned int* w, int* flag, int* gcur) {
    int t = threadIdx.x;
    gcur[t] = t << CAPSH;
    if (t < 64) {
        unsigned int v = w[2 * t + 1];
        unsigned long long m = __ballot(v != 0u);
        if (t == 0) *flag = (m == 0ull) ? 1 : 0;   // 1 => int64
    }
}

// ---------------------------------------------------------------------------
// Scatter packed (src<<8 | dst&255) into per-bucket slack regions.
// ---------------------------------------------------------------------------
__global__ __launch_bounds__(TPB) void p3_scatter(const void* ei, long long E,
                                                  const int* flag, int* gcur,
                                                  int* pairs) {
    __shared__ int cnt[TPB];
    __shared__ int cur2[TPB];
    int t = threadIdx.x;
    cnt[t] = 0;
    __syncthreads();
    int is64 = *flag;
    long long chunk = (E + gridDim.x - 1) / gridDim.x;
    long long s0 = (long long)blockIdx.x * chunk;
    long long s1 = (s0 + chunk < E) ? s0 + chunk : E;
    for (long long e = s0 + t; e < s1; e += TPB) {
        int d = ld_idx(ei, E + e, is64);
        atomicAdd(&cnt[d >> 8], 1);
    }
    __syncthreads();
    if (cnt[t]) cur2[t] = atomicAdd(&gcur[t], cnt[t]);
    __syncthreads();
    for (long long e = s0 + t; e < s1; e += TPB) {
        int sv = ld_idx(ei, e, is64);
        int d  = ld_idx(ei, E + e, is64);
        int pos = atomicAdd(&cur2[d >> 8], 1);
        pairs[pos] = (sv << 8) | (d & 255);
    }
}

// ---------------------------------------------------------------------------
// One block per bucket: degree count (LDS atomics) -> 256-wide scan -> meta,
// then csr scatter via LDS cursors. All global traffic bucket-local.
// ---------------------------------------------------------------------------
__global__ __launch_bounds__(TPB) void p4_fill(const int* __restrict__ pairs,
                                               const int* __restrict__ gcur,
                                               int2* __restrict__ meta,
                                               int* __restrict__ csr, int N) {
    __shared__ int ldeg[TPB];
    __shared__ int ssc[TPB];
    __shared__ int cur[TPB];
    int t = threadIdx.x;
    int b = blockIdx.x;
    int base = b << CAPSH;
    int ecnt = gcur[b] - base;                   // edges in this bucket
    ldeg[t] = 0;
    __syncthreads();
    for (int e = base + t; e < base + ecnt; e += TPB)
        atomicAdd(&ldeg[pairs[e] & 255], 1);
    __syncthreads();
    int dv = ldeg[t];
    ssc[t] = dv;
    __syncthreads();
    for (int off = 1; off < TPB; off <<= 1) {
        int u = 0;
        if (t >= off) u = ssc[t - off];
        __syncthreads();
        ssc[t] += u;
        __syncthreads();
    }
    int o = base + ssc[t] - dv;                  // absolute exclusive offset
    cur[t] = o;
    int node = (b << 8) + t;
    if (node < N)
        meta[node] = make_int2((o << 10) | dv,
                               __float_as_int(rsqrtf((float)(dv + 1))));
    __syncthreads();
    for (int e = base + t; e < base + ecnt; e += TPB) {
        int p = pairs[e];
        int pos = atomicAdd(&cur[p & 255], 1);
        csr[pos] = p >> 8;
    }
}

// fp16 row helpers: rows are 64 halves = 128 B = 16 x ushort4.
__device__ __forceinline__ float4 h4_to_f4(ushort4 v) {
    float4 r;
    r.x = __half2float(__ushort_as_half(v.x));
    r.y = __half2float(__ushort_as_half(v.y));
    r.z = __half2float(__ushort_as_half(v.z));
    r.w = __half2float(__ushort_as_half(v.w));
    return r;
}

__device__ __forceinline__ ushort4 f4_to_h4(float4 v) {
    ushort4 r;
    r.x = __half_as_ushort(__float2half_rn(v.x));
    r.y = __half_as_ushort(__float2half_rn(v.y));
    r.z = __half_as_ushort(__float2half_rn(v.z));
    r.w = __half_as_ushort(__float2half_rn(v.w));
    return r;
}

// Cooperative gather (fp16 rows): 16 lanes batch-load 16 CSR indices in one
// coalesced read, broadcast via __shfl, then issue up to 16 INDEPENDENT 8B
// row-chunk loads.  threadIdx.x&48 == (lane within wave)&48 for TPB=256.
__device__ __forceinline__ float4 gather_rows(const ushort4* __restrict__ y4,
                                              const int* __restrict__ csr,
                                              int start, int cnt, int c,
                                              float4 acc) {
    const int base = threadIdx.x & 48;           // group base lane within wave
    int j = 0;
    while (j + 16 <= cnt) {
        int idx = csr[start + j + c];
        #pragma unroll
        for (int k = 0; k < 16; ++k) {
            int s = __shfl(idx, base + k);
            float4 v = h4_to_f4(y4[s * 16 + c]);
            acc.x += v.x; acc.y += v.y; acc.z += v.z; acc.w += v.w;
        }
        j += 16;
    }
    int rem = cnt - j;                           // 0..15, group-uniform
    if (rem > 0) {
        int idx = (c < rem) ? csr[start + j + c] : 0;
        #pragma unroll
        for (int k = 0; k < 15; ++k) {
            if (k < rem) {
                int s = __shfl(idx, base + k);
                float4 v = h4_to_f4(y4[s * 16 + c]);
                acc.x += v.x; acc.y += v.y; acc.z += v.z; acc.w += v.w;
            }
        }
    }
    return acc;
}

// ---------------------------------------------------------------------------
// Layer-0: y0 = fp16(dis * (x @ W0)).  64 nodes/block, 16 nodes/wave.
// ---------------------------------------------------------------------------
__global__ __launch_bounds__(TPB) void mm_first(const float* __restrict__ x,
                                                const float* __restrict__ W,
                                                const int2* __restrict__ meta,
                                                ushort4* __restrict__ yout, int n) {
    __shared__ float Ws[64 * 64];
    __shared__ float hs[4][16][68];
    int t = threadIdx.x;
    float4* Ws4 = (float4*)Ws;
    const float4* W4g = (const float4*)W;
    #pragma unroll
    for (int i = 0; i < 4; ++i) Ws4[t + i * TPB] = W4g[t + i * TPB];
    __syncthreads();

    int wave = t >> 6, lane = t & 63;
    int g = lane >> 4, c = lane & 15;
    int rowbase = g * 4;
    int nodebase = blockIdx.x * 64 + wave * 16 + rowbase;

    float dvv[4];
    #pragma unroll
    for (int m = 0; m < 4; ++m) {
        int node = nodebase + m;
        float4 h = {0.f, 0.f, 0.f, 0.f};
        float dv = 0.f;
        if (node < n) {
            dv = __int_as_float(meta[node].y);
            h = ((const float4*)x)[node * 16 + c];
        }
        dvv[m] = dv;
        *(float4*)&hs[wave][rowbase + m][c * 4] = h;   // wave-private: no barrier
    }

    float4 o[4];
    #pragma unroll
    for (int m = 0; m < 4; ++m) o[m] = make_float4(0.f, 0.f, 0.f, 0.f);
    #pragma unroll
    for (int k = 0; k < 64; ++k) {
        float4 w4 = Ws4[k * 16 + c];
        float h0 = hs[wave][rowbase + 0][k];
        float h1 = hs[wave][rowbase + 1][k];
        float h2 = hs[wave][rowbase + 2][k];
        float h3 = hs[wave][rowbase + 3][k];
        o[0].x = fmaf(h0, w4.x, o[0].x); o[0].y = fmaf(h0, w4.y, o[0].y);
        o[0].z = fmaf(h0, w4.z, o[0].z); o[0].w = fmaf(h0, w4.w, o[0].w);
        o[1].x = fmaf(h1, w4.x, o[1].x); o[1].y = fmaf(h1, w4.y, o[1].y);
        o[1].z = fmaf(h1, w4.z, o[1].z); o[1].w = fmaf(h1, w4.w, o[1].w);
        o[2].x = fmaf(h2, w4.x, o[2].x); o[2].y = fmaf(h2, w4.y, o[2].y);
        o[2].z = fmaf(h2, w4.z, o[2].z); o[2].w = fmaf(h2, w4.w, o[2].w);
        o[3].x = fmaf(h3, w4.x, o[3].x); o[3].y = fmaf(h3, w4.y, o[3].y);
        o[3].z = fmaf(h3, w4.z, o[3].z); o[3].w = fmaf(h3, w4.w, o[3].w);
    }
    #pragma unroll
    for (int m = 0; m < 4; ++m) {
        int node = nodebase + m;
        if (node < n) {
            float dv = dvv[m];
            float4 r = {o[m].x * dv, o[m].y * dv, o[m].z * dv, o[m].w * dv};
            yout[node * 16 + c] = f4_to_h4(r);
        }
    }
}

// ---------------------------------------------------------------------------
// Fused: h = relu(dis*(y + agg y[src]) + b); yout = fp16(dis * (h @ W)).
// 64 nodes/block, 16 nodes/wave (4 sequential gathers per 16-lane group).
// ---------------------------------------------------------------------------
__global__ __launch_bounds__(TPB) void agg_mm(const ushort4* __restrict__ y,
                                              const int* __restrict__ csr,
                                              const int2* __restrict__ meta,
                                              const float* __restrict__ b,
                                              const float* __restrict__ W,
                                              ushort4* __restrict__ yout, int n) {
    __shared__ float Ws[64 * 64];
    __shared__ float hs[4][16][68];
    int t = threadIdx.x;
    float4* Ws4 = (float4*)Ws;
    const float4* W4g = (const float4*)W;
    #pragma unroll
    for (int i = 0; i < 4; ++i) Ws4[t + i * TPB] = W4g[t + i * TPB];
    __syncthreads();

    int wave = t >> 6, lane = t & 63;
    int g = lane >> 4, c = lane & 15;
    int rowbase = g * 4;
    int nodebase = blockIdx.x * 64 + wave * 16 + rowbase;
    float4 bb = ((const float4*)b)[c];

    float dvv[4];
    #pragma unroll
    for (int m = 0; m < 4; ++m) {
        int node = nodebase + m;
        float4 h = {0.f, 0.f, 0.f, 0.f};
        float dv = 0.f;
        if (node < n) {                          // group-uniform
            int2 mt = meta[node];
            int start = ((unsigned)mt.x) >> 10;
            int cnt = mt.x & 1023;
            dv = __int_as_float(mt.y);
            float4 acc = h4_to_f4(y[node * 16 + c]);     // self-loop term
            acc = gather_rows(y, csr, start, cnt, c, acc);
            h.x = fmaxf(fmaf(dv, acc.x, bb.x), 0.f);
            h.y = fmaxf(fmaf(dv, acc.y, bb.y), 0.f);
            h.z = fmaxf(fmaf(dv, acc.z, bb.z), 0.f);
            h.w = fmaxf(fmaf(dv, acc.w, bb.w), 0.f);
        }
        dvv[m] = dv;
        *(float4*)&hs[wave][rowbase + m][c * 4] = h;   // wave-private
    }

    float4 o[4];
    #pragma unroll
    for (int m = 0; m < 4; ++m) o[m] = make_float4(0.f, 0.f, 0.f, 0.f);
    #pragma unroll
    for (int k = 0; k < 64; ++k) {
        float4 w4 = Ws4[k * 16 + c];
        float h0 = hs[wave][rowbase + 0][k];
        float h1 = hs[wave][rowbase + 1][k];
        float h2 = hs[wave][rowbase + 2][k];
        float h3 = hs[wave][rowbase + 3][k];
        o[0].x = fmaf(h0, w4.x, o[0].x); o[0].y = fmaf(h0, w4.y, o[0].y);
        o[0].z = fmaf(h0, w4.z, o[0].z); o[0].w = fmaf(h0, w4.w, o[0].w);
        o[1].x = fmaf(h1, w4.x, o[1].x); o[1].y = fmaf(h1, w4.y, o[1].y);
        o[1].z = fmaf(h1, w4.z, o[1].z); o[1].w = fmaf(h1, w4.w, o[1].w);
        o[2].x = fmaf(h2, w4.x, o[2].x); o[2].y = fmaf(h2, w4.y, o[2].y);
        o[2].z = fmaf(h2, w4.z, o[2].z); o[2].w = fmaf(h2, w4.w, o[2].w);
        o[3].x = fmaf(h3, w4.x, o[3].x); o[3].y = fmaf(h3, w4.y, o[3].y);
        o[3].z = fmaf(h3, w4.z, o[3].z); o[3].w = fmaf(h3, w4.w, o[3].w);
    }
    #pragma unroll
    for (int m = 0; m < 4; ++m) {
        int node = nodebase + m;
        if (node < n) {
            float dv = dvv[m];
            float4 r = {o[m].x * dv, o[m].y * dv, o[m].z * dv, o[m].w * dv};
            yout[node * 16 + c] = f4_to_h4(r);
        }
    }
}

// ---------------------------------------------------------------------------
// Last layer: h = relu(dis*(agg y)+b2); out = h @ linW + linb  (64 -> 8).
// Lane c of a group: node msel=c>>3 (+2), col=c&7 -> all 16 lanes active.
// ---------------------------------------------------------------------------
__global__ __launch_bounds__(TPB) void agg_final(const ushort4* __restrict__ y,
                                                 const int* __restrict__ csr,
                                                 const int2* __restrict__ meta,
                                                 const float* __restrict__ b,
                                                 const float* __restrict__ Wl,
                                                 const float* __restrict__ bl,
                                                 float* __restrict__ out, int n) {
    __shared__ float Wls[64 * 8];
    __shared__ float bls[8];
    __shared__ float hs[4][16][68];
    int t = threadIdx.x;
    if (t < 128) ((float4*)Wls)[t] = ((const float4*)Wl)[t];
    if (t < 8) bls[t] = bl[t];
    __syncthreads();

    int wave = t >> 6, lane = t & 63;
    int g = lane >> 4, c = lane & 15;
    int rowbase = g * 4;
    int nodebase = blockIdx.x * 64 + wave * 16 + rowbase;
    float4 bb = ((const float4*)b)[c];

    #pragma unroll
    for (int m = 0; m < 4; ++m) {
        int node = nodebase + m;
        float4 h = {0.f, 0.f, 0.f, 0.f};
        if (node < n) {
            int2 mt = meta[node];
            int start = ((unsigned)mt.x) >> 10;
            int cnt = mt.x & 1023;
            float dv = __int_as_float(mt.y);
            float4 acc = h4_to_f4(y[node * 16 + c]);
            acc = gather_rows(y, csr, start, cnt, c, acc);
            h.x = fmaxf(fmaf(dv, acc.x, bb.x), 0.f);
            h.y = fmaxf(fmaf(dv, acc.y, bb.y), 0.f);
            h.z = fmaxf(fmaf(dv, acc.z, bb.z), 0.f);
            h.w = fmaxf(fmaf(dv, acc.w, bb.w), 0.f);
        }
        *(float4*)&hs[wave][rowbase + m][c * 4] = h;   // wave-private
    }

    int col = c & 7;
    int msel = c >> 3;                           // 0 or 1
    float a0 = bls[col], a1 = bls[col];
    #pragma unroll
    for (int k = 0; k < 64; ++k) {
        float w = Wls[k * 8 + col];
        a0 = fmaf(hs[wave][rowbase + msel][k], w, a0);
        a1 = fmaf(hs[wave][rowbase + msel + 2][k], w, a1);
    }
    int n0 = nodebase + msel, n1 = nodebase + msel + 2;
    if (n0 < n) out[n0 * 8 + col] = a0;
    if (n1 < n) out[n1 * 8 + col] = a1;
}

extern "C" void kernel_launch(void* const* d_in, const int* in_sizes, int n_in,
                              void* d_out, int out_size, void* d_ws, size_t ws_size,
                              hipStream_t stream) {
    const float* x  = (const float*)d_in[0];
    const void*  ei = d_in[1];
    const float* W0 = (const float*)d_in[2];
    const float* b0 = (const float*)d_in[3];
    const float* W1 = (const float*)d_in[4];
    const float* b1 = (const float*)d_in[5];
    const float* W2 = (const float*)d_in[6];
    const float* b2 = (const float*)d_in[7];
    const float* Wl = (const float*)d_in[8];
    const float* bl = (const float*)d_in[9];

    const long long E = in_sizes[1] / 2;                 // 800000
    const int dh = in_sizes[3];                          // 64
    const int din = in_sizes[2] / dh;                    // 64
    const int N = in_sizes[0] / din;                     // 50000
    const int nb = (N + 255) >> 8;                       // 196 buckets

    // Workspace carve (256-aligned): ~26.5 MB total
    char* ws = (char*)d_ws;
    size_t off = 0;
    auto alloc = [&](size_t bytes) -> char* {
        char* r = ws + off;
        off += (bytes + 255) & ~(size_t)255;
        return r;
    };
    int*     flag    = (int*)    alloc(4);
    int*     gcur    = (int*)    alloc(1024);
    int2*    meta    = (int2*)   alloc((size_t)N * 8);
    int*     pairs   = (int*)    alloc((size_t)nb * CAP * 4);   // 6.4 MB slack
    int*     csr     = (int*)    alloc((size_t)nb * CAP * 4);   // 6.4 MB slack
    ushort4* ybA     = (ushort4*)alloc((size_t)N * 64 * 2);     // fp16 rows
    ushort4* ybB     = (ushort4*)alloc((size_t)N * 64 * 2);

    // --- preprocessing: 3 kernels ---
    init_all<<<1, TPB, 0, stream>>>((const unsigned int*)ei, flag, gcur);
    p3_scatter<<<256, TPB, 0, stream>>>(ei, E, flag, gcur, pairs);
    p4_fill<<<nb, TPB, 0, stream>>>(pairs, gcur, meta, csr, N);

    // --- layers: 64 nodes/block ---
    const int gL = (N + 63) / 64;                        // 782
    mm_first<<<gL, TPB, 0, stream>>>(x, W0, meta, ybA, N);
    agg_mm<<<gL, TPB, 0, stream>>>(ybA, csr, meta, b0, W1, ybB, N);
    agg_mm<<<gL, TPB, 0, stream>>>(ybB, csr, meta, b1, W2, ybA, N);
    agg_final<<<gL, TPB, 0, stream>>>(ybA, csr, meta, b2, Wl, bl,
                                      (float*)d_out, N);
}

// Round 10
// 216.238 us; speedup vs baseline: 1.9046x; 1.9046x over previous
//
#include <hip/hip_runtime.h>
#include <hip/hip_fp16.h>

#define TPB 256
#define CAP 8192           // slack entries per 256-node bucket (avg fill ~4082)
#define CAPSH 13           // log2(CAP)

// Identity used: dis⊙(x@W) = (dis⊙x)@W and Agg(z@W) = (Agg z)@W, so each
// layer is gather(z) -> mm -> relu, with z = fp16(dis ⊙ activation).
// Buckets: 256 nodes each (dst>>8). Bucket b owns pairs[b*CAP..) and
// csr[b*CAP..) -> no cross-bucket scan. meta[v] = {(offset<<10)|deg, dis}.
// Layer kernels use the R5-PROVEN shape: 16 nodes/block, 16 threads/node,
// 4 concurrent gathers per wave, ~20KB LDS -> high occupancy for the
// latency-bound gather (R9 showed 16 nodes/wave -> VGPR 236 -> 8.8% occ).

__device__ __forceinline__ int ld_idx(const void* p, long long i, int is64) {
    return is64 ? (int)((const long long*)p)[i] : ((const int*)p)[i];
}

// fp16 row helpers: rows are 64 halves = 128 B = 16 x ushort4.
__device__ __forceinline__ float4 h4_to_f4(ushort4 v) {
    float4 r;
    r.x = __half2float(__ushort_as_half(v.x));
    r.y = __half2float(__ushort_as_half(v.y));
    r.z = __half2float(__ushort_as_half(v.z));
    r.w = __half2float(__ushort_as_half(v.w));
    return r;
}

__device__ __forceinline__ ushort4 f4_to_h4(float4 v) {
    ushort4 r;
    r.x = __half_as_ushort(__float2half_rn(v.x));
    r.y = __half_as_ushort(__float2half_rn(v.y));
    r.z = __half_as_ushort(__float2half_rn(v.z));
    r.w = __half_as_ushort(__float2half_rn(v.w));
    return r;
}

// ---------------------------------------------------------------------------
// Scatter packed (src<<8 | dst&255) into per-bucket slack regions. gcur must
// be zeroed (hipMemsetAsync). Per-block edge-dtype detect (int64 => odd words
// of first 64 entries all zero).
// ---------------------------------------------------------------------------
__global__ __launch_bounds__(TPB) void p3_scatter(const void* ei, long long E,
                                                  int* gcur, int* pairs) {
    __shared__ int cnt[TPB];
    __shared__ int cur2[TPB];
    __shared__ int s_is64;
    int t = threadIdx.x;
    if (t < 64) {
        const unsigned int* w = (const unsigned int*)ei;
        unsigned long long m = __ballot(w[2 * t + 1] != 0u);
        if (t == 0) s_is64 = (m == 0ull) ? 1 : 0;
    }
    cnt[t] = 0;
    __syncthreads();
    const int is64 = s_is64;
    long long chunk = (E + gridDim.x - 1) / gridDim.x;
    long long s0 = (long long)blockIdx.x * chunk;
    long long s1 = (s0 + chunk < E) ? s0 + chunk : E;
    for (long long e = s0 + t; e < s1; e += TPB) {
        int d = ld_idx(ei, E + e, is64);
        atomicAdd(&cnt[d >> 8], 1);
    }
    __syncthreads();
    if (cnt[t]) cur2[t] = (t << CAPSH) + atomicAdd(&gcur[t], cnt[t]);
    __syncthreads();
    for (long long e = s0 + t; e < s1; e += TPB) {
        int sv = ld_idx(ei, e, is64);
        int d  = ld_idx(ei, E + e, is64);
        int pos = atomicAdd(&cur2[d >> 8], 1);
        pairs[pos] = (sv << 8) | (d & 255);
    }
}

// ---------------------------------------------------------------------------
// One block per bucket: degree count (LDS atomics) -> 256-wide scan -> meta,
// csr scatter via LDS cursors, then z0 = fp16(dis * x) for this bucket's
// 256 nodes (coalesced: lane c reads float4 c of node p*16+ni).
// ---------------------------------------------------------------------------
__global__ __launch_bounds__(TPB) void p4_fill(const int* __restrict__ pairs,
                                               const int* __restrict__ gcur,
                                               const float* __restrict__ x,
                                               int2* __restrict__ meta,
                                               int* __restrict__ csr,
                                               ushort4* __restrict__ z0, int N) {
    __shared__ int ldeg[TPB];
    __shared__ int ssc[TPB];
    __shared__ int cur[TPB];
    __shared__ float fdis[TPB];
    int t = threadIdx.x;
    int b = blockIdx.x;
    int base = b << CAPSH;
    int ecnt = gcur[b];                          // edges in this bucket
    ldeg[t] = 0;
    __syncthreads();
    for (int e = base + t; e < base + ecnt; e += TPB)
        atomicAdd(&ldeg[pairs[e] & 255], 1);
    __syncthreads();
    int dv = ldeg[t];
    ssc[t] = dv;
    __syncthreads();
    for (int off = 1; off < TPB; off <<= 1) {
        int u = 0;
        if (t >= off) u = ssc[t - off];
        __syncthreads();
        ssc[t] += u;
        __syncthreads();
    }
    int o = base + ssc[t] - dv;                  // absolute exclusive offset
    cur[t] = o;
    float dd = rsqrtf((float)(dv + 1));          // +1 self loop
    fdis[t] = dd;
    int node = (b << 8) + t;
    if (node < N)
        meta[node] = make_int2((o << 10) | dv, __float_as_int(dd));
    __syncthreads();
    for (int e = base + t; e < base + ecnt; e += TPB) {
        int p = pairs[e];
        int pos = atomicAdd(&cur[p & 255], 1);
        csr[pos] = p >> 8;
    }

    // z0 conversion: 16 passes, 16 nodes each, coalesced float4 reads.
    int ni = t >> 4, c = t & 15;
    for (int p = 0; p < 16; ++p) {
        int nd = (b << 8) + p * 16 + ni;
        if (nd < N) {
            float dvv = fdis[p * 16 + ni];
            float4 h = ((const float4*)x)[nd * 16 + c];
            float4 r = {h.x * dvv, h.y * dvv, h.z * dvv, h.w * dvv};
            z0[nd * 16 + c] = f4_to_h4(r);
        }
    }
}

// Cooperative gather (fp16 rows): 16 lanes batch-load 16 CSR indices in one
// coalesced read, broadcast via __shfl, then issue up to 16 INDEPENDENT 8B
// row-chunk loads. threadIdx.x&48 == wave-lane&48 for TPB=256.
__device__ __forceinline__ float4 gather_rows(const ushort4* __restrict__ y4,
                                              const int* __restrict__ csr,
                                              int start, int cnt, int c,
                                              float4 acc) {
    const int base = threadIdx.x & 48;           // group base lane within wave
    int j = 0;
    while (j + 16 <= cnt) {
        int idx = csr[start + j + c];
        #pragma unroll
        for (int k = 0; k < 16; ++k) {
            int s = __shfl(idx, base + k);
            float4 v = h4_to_f4(y4[s * 16 + c]);
            acc.x += v.x; acc.y += v.y; acc.z += v.z; acc.w += v.w;
        }
        j += 16;
    }
    int rem = cnt - j;                           // 0..15, group-uniform
    if (rem > 0) {
        int idx = (c < rem) ? csr[start + j + c] : 0;
        #pragma unroll
        for (int k = 0; k < 15; ++k) {
            if (k < rem) {
                int s = __shfl(idx, base + k);
                float4 v = h4_to_f4(y4[s * 16 + c]);
                acc.x += v.x; acc.y += v.y; acc.z += v.z; acc.w += v.w;
            }
        }
    }
    return acc;
}

// ---------------------------------------------------------------------------
// Layer: s = z_v + Agg z_u (gather); u = s @ W; zout = fp16(dis*relu(dis*u+b)).
// 16 nodes/block, 16 threads/node (R5-proven shape). W staged to LDS during
// the gather; barrier only afterwards.
// ---------------------------------------------------------------------------
__global__ __launch_bounds__(TPB) void layer_mm(const ushort4* __restrict__ z,
                                                const int* __restrict__ csr,
                                                const int2* __restrict__ meta,
                                                const float* __restrict__ b,
                                                const float* __restrict__ W,
                                                ushort4* __restrict__ zout, int n) {
    __shared__ float Ws[64 * 64];
    __shared__ float hs[16][68];                 // +4 pad kills bank conflicts
    int t = threadIdx.x;
    float4* Ws4 = (float4*)Ws;
    const float4* W4g = (const float4*)W;
    #pragma unroll
    for (int i = 0; i < 4; ++i) Ws4[t + i * TPB] = W4g[t + i * TPB];

    int ni = t >> 4, c = t & 15;
    int node = blockIdx.x * 16 + ni;
    float4 s = {0.f, 0.f, 0.f, 0.f};
    float dv = 0.f;
    if (node < n) {
        int2 m = meta[node];
        int start = ((unsigned)m.x) >> 10;
        int cnt = m.x & 1023;
        dv = __int_as_float(m.y);
        s = h4_to_f4(z[node * 16 + c]);          // self-loop term z_v
        s = gather_rows(z, csr, start, cnt, c, s);
    }
    __syncthreads();                             // Ws fully staged
    *(float4*)&hs[ni][c * 4] = s;                // wave-private: no barrier
    float4 u = {0.f, 0.f, 0.f, 0.f};
    #pragma unroll
    for (int k = 0; k < 64; ++k) {
        float hv = hs[ni][k];
        float4 w = Ws4[k * 16 + c];
        u.x = fmaf(hv, w.x, u.x);
        u.y = fmaf(hv, w.y, u.y);
        u.z = fmaf(hv, w.z, u.z);
        u.w = fmaf(hv, w.w, u.w);
    }
    if (node < n) {
        float4 bb = ((const float4*)b)[c];
        float4 r;
        r.x = fmaxf(fmaf(dv, u.x, bb.x), 0.f) * dv;
        r.y = fmaxf(fmaf(dv, u.y, bb.y), 0.f) * dv;
        r.z = fmaxf(fmaf(dv, u.z, bb.z), 0.f) * dv;
        r.w = fmaxf(fmaf(dv, u.w, bb.w), 0.f) * dv;
        zout[node * 16 + c] = f4_to_h4(r);       // z_{l+1} = dis*relu(...)
    }
}

// ---------------------------------------------------------------------------
// Final: s = gather(z2); h = relu(dis*(s@W2)+b2); out = h @ linW + linb.
// ---------------------------------------------------------------------------
__global__ __launch_bounds__(TPB) void layer_final(const ushort4* __restrict__ z,
                                                   const int* __restrict__ csr,
                                                   const int2* __restrict__ meta,
                                                   const float* __restrict__ b,
                                                   const float* __restrict__ W,
                                                   const float* __restrict__ Wl,
                                                   const float* __restrict__ bl,
                                                   float* __restrict__ out, int n) {
    __shared__ float Ws[64 * 64];
    __shared__ float Wls[64 * 8];
    __shared__ float bls[8];
    __shared__ float hs[16][68];
    int t = threadIdx.x;
    float4* Ws4 = (float4*)Ws;
    const float4* W4g = (const float4*)W;
    #pragma unroll
    for (int i = 0; i < 4; ++i) Ws4[t + i * TPB] = W4g[t + i * TPB];
    if (t < 128) ((float4*)Wls)[t] = ((const float4*)Wl)[t];
    if (t < 8) bls[t] = bl[t];

    int ni = t >> 4, c = t & 15;
    int node = blockIdx.x * 16 + ni;
    float4 s = {0.f, 0.f, 0.f, 0.f};
    float dv = 0.f;
    if (node < n) {
        int2 m = meta[node];
        int start = ((unsigned)m.x) >> 10;
        int cnt = m.x & 1023;
        dv = __int_as_float(m.y);
        s = h4_to_f4(z[node * 16 + c]);
        s = gather_rows(z, csr, start, cnt, c, s);
    }
    __syncthreads();                             // Ws/Wls/bls staged
    *(float4*)&hs[ni][c * 4] = s;                // wave-private
    float4 u = {0.f, 0.f, 0.f, 0.f};
    #pragma unroll
    for (int k = 0; k < 64; ++k) {
        float hv = hs[ni][k];
        float4 w = Ws4[k * 16 + c];
        u.x = fmaf(hv, w.x, u.x);
        u.y = fmaf(hv, w.y, u.y);
        u.z = fmaf(hv, w.z, u.z);
        u.w = fmaf(hv, w.w, u.w);
    }
    float4 bb = ((const float4*)b)[c];
    float4 h4;
    h4.x = fmaxf(fmaf(dv, u.x, bb.x), 0.f);
    h4.y = fmaxf(fmaf(dv, u.y, bb.y), 0.f);
    h4.z = fmaxf(fmaf(dv, u.z, bb.z), 0.f);
    h4.w = fmaxf(fmaf(dv, u.w, bb.w), 0.f);
    // All lanes of this wave finished reading hs[ni] (program order) before
    // any lane's overwrite below -- wave-lockstep makes this safe.
    *(float4*)&hs[ni][c * 4] = h4;
    if (c < 8 && node < n) {
        float acc = bls[c];
        #pragma unroll
        for (int k = 0; k < 64; ++k)
            acc = fmaf(hs[ni][k], Wls[k * 8 + c], acc);
        out[node * 8 + c] = acc;
    }
}

extern "C" void kernel_launch(void* const* d_in, const int* in_sizes, int n_in,
                              void* d_out, int out_size, void* d_ws, size_t ws_size,
                              hipStream_t stream) {
    const float* x  = (const float*)d_in[0];
    const void*  ei = d_in[1];
    const float* W0 = (const float*)d_in[2];
    const float* b0 = (const float*)d_in[3];
    const float* W1 = (const float*)d_in[4];
    const float* b1 = (const float*)d_in[5];
    const float* W2 = (const float*)d_in[6];
    const float* b2 = (const float*)d_in[7];
    const float* Wl = (const float*)d_in[8];
    const float* bl = (const float*)d_in[9];

    const long long E = in_sizes[1] / 2;                 // 800000
    const int dh = in_sizes[3];                          // 64
    const int din = in_sizes[2] / dh;                    // 64
    const int N = in_sizes[0] / din;                     // 50000
    const int nb = (N + 255) >> 8;                       // 196 buckets

    // Workspace carve (256-aligned): ~26.5 MB total
    char* ws = (char*)d_ws;
    size_t off = 0;
    auto alloc = [&](size_t bytes) -> char* {
        char* r = ws + off;
        off += (bytes + 255) & ~(size_t)255;
        return r;
    };
    int*     gcur    = (int*)    alloc(1024);
    int2*    meta    = (int2*)   alloc((size_t)N * 8);
    int*     pairs   = (int*)    alloc((size_t)nb * CAP * 4);   // 6.4 MB slack
    int*     csr     = (int*)    alloc((size_t)nb * CAP * 4);   // 6.4 MB slack
    ushort4* zbA     = (ushort4*)alloc((size_t)N * 64 * 2);     // fp16 rows
    ushort4* zbB     = (ushort4*)alloc((size_t)N * 64 * 2);

    // --- preprocessing ---
    hipMemsetAsync(gcur, 0, 256 * sizeof(int), stream);
    p3_scatter<<<256, TPB, 0, stream>>>(ei, E, gcur, pairs);
    p4_fill<<<nb, TPB, 0, stream>>>(pairs, gcur, x, meta, csr, zbA, N);

    // --- 3 layers: gather -> mm -> relu (mm_first eliminated by linearity) ---
    const int gL = (N + 15) / 16;                        // 3125
    layer_mm<<<gL, TPB, 0, stream>>>(zbA, csr, meta, b0, W0, zbB, N);
    layer_mm<<<gL, TPB, 0, stream>>>(zbB, csr, meta, b1, W1, zbA, N);
    layer_final<<<gL, TPB, 0, stream>>>(zbA, csr, meta, b2, W2, Wl, bl,
                                        (float*)d_out, N);
}

// Round 11
// 212.345 us; speedup vs baseline: 1.9395x; 1.0183x over previous
//
#include <hip/hip_runtime.h>
#include <hip/hip_fp16.h>

#define TPB 256
#define CAP 16384          // slack entries per 256-node bucket (padded fill ~6000)
#define CAPSH 14           // log2(CAP)

// Identity used: dis⊙(x@W) = (dis⊙x)@W and Agg(z@W) = (Agg z)@W, so each
// layer is gather(z) -> mm -> relu, with z = fp16(dis ⊙ activation).
// Buckets: 256 nodes each (dst>>8). Bucket b owns pairs[b*CAP..) and
// csr[b*CAP..). Each node's CSR run is PADDED to a multiple of 16 with the
// index N (a dedicated all-zero z row) -> gather is a uniform batch loop,
// no remainder tail, no inter-group divergence.
// meta[v] = { (offset<<7) | nbatches, bitcast(dis) }.
// mm uses __shfl to broadcast s (distributed across the 16 lanes of a group)
// instead of an LDS hs round-trip: LDS per k-step 17.8 -> 12 cyc (-33%),
// the binding pipe of the layer kernels (R8/R9 evidence).

__device__ __forceinline__ int ld_idx(const void* p, long long i, int is64) {
    return is64 ? (int)((const long long*)p)[i] : ((const int*)p)[i];
}

// fp16 row helpers: rows are 64 halves = 128 B = 16 x ushort4.
__device__ __forceinline__ float4 h4_to_f4(ushort4 v) {
    float4 r;
    r.x = __half2float(__ushort_as_half(v.x));
    r.y = __half2float(__ushort_as_half(v.y));
    r.z = __half2float(__ushort_as_half(v.z));
    r.w = __half2float(__ushort_as_half(v.w));
    return r;
}

__device__ __forceinline__ ushort4 f4_to_h4(float4 v) {
    ushort4 r;
    r.x = __half_as_ushort(__float2half_rn(v.x));
    r.y = __half_as_ushort(__float2half_rn(v.y));
    r.z = __half_as_ushort(__float2half_rn(v.z));
    r.w = __half_as_ushort(__float2half_rn(v.w));
    return r;
}

// ---------------------------------------------------------------------------
// Scatter packed (src<<8 | dst&255) into per-bucket slack regions. gcur must
// be zeroed (hipMemsetAsync). Per-block edge-dtype detect.
// ---------------------------------------------------------------------------
__global__ __launch_bounds__(TPB) void p3_scatter(const void* ei, long long E,
                                                  int* gcur, int* pairs) {
    __shared__ int cnt[TPB];
    __shared__ int cur2[TPB];
    __shared__ int s_is64;
    int t = threadIdx.x;
    if (t < 64) {
        const unsigned int* w = (const unsigned int*)ei;
        unsigned long long m = __ballot(w[2 * t + 1] != 0u);
        if (t == 0) s_is64 = (m == 0ull) ? 1 : 0;
    }
    cnt[t] = 0;
    __syncthreads();
    const int is64 = s_is64;
    long long chunk = (E + gridDim.x - 1) / gridDim.x;
    long long s0 = (long long)blockIdx.x * chunk;
    long long s1 = (s0 + chunk < E) ? s0 + chunk : E;
    for (long long e = s0 + t; e < s1; e += TPB) {
        int d = ld_idx(ei, E + e, is64);
        atomicAdd(&cnt[d >> 8], 1);
    }
    __syncthreads();
    if (cnt[t]) cur2[t] = (t << CAPSH) + atomicAdd(&gcur[t], cnt[t]);
    __syncthreads();
    for (long long e = s0 + t; e < s1; e += TPB) {
        int sv = ld_idx(ei, e, is64);
        int d  = ld_idx(ei, E + e, is64);
        int pos = atomicAdd(&cur2[d >> 8], 1);
        pairs[pos] = (sv << 8) | (d & 255);
    }
}

// ---------------------------------------------------------------------------
// One block per bucket: degree count (LDS atomics) -> padded 256-wide scan
// -> meta, csr scatter via LDS cursors + pad-to-16 with index N, then
// z0 = fp16(dis * x) for this bucket's 256 nodes. Block 0 zeroes z0 row N.
// ---------------------------------------------------------------------------
__global__ __launch_bounds__(TPB) void p4_fill(const int* __restrict__ pairs,
                                               const int* __restrict__ gcur,
                                               const float* __restrict__ x,
                                               int2* __restrict__ meta,
                                               int* __restrict__ csr,
                                               ushort4* __restrict__ z0, int N) {
    __shared__ int ldeg[TPB];
    __shared__ int ssc[TPB];
    __shared__ int cur[TPB];
    __shared__ float fdis[TPB];
    int t = threadIdx.x;
    int b = blockIdx.x;
    int base = b << CAPSH;
    int ecnt = gcur[b];                          // real edges in this bucket
    ldeg[t] = 0;
    __syncthreads();
    for (int e = base + t; e < base + ecnt; e += TPB)
        atomicAdd(&ldeg[pairs[e] & 255], 1);
    __syncthreads();
    int dv = ldeg[t];
    int pv = (dv + 15) & ~15;                    // padded to multiple of 16
    ssc[t] = pv;
    __syncthreads();
    for (int off = 1; off < TPB; off <<= 1) {
        int u = 0;
        if (t >= off) u = ssc[t - off];
        __syncthreads();
        ssc[t] += u;
        __syncthreads();
    }
    int o = base + ssc[t] - pv;                  // absolute padded offset
    cur[t] = o;
    float dd = rsqrtf((float)(dv + 1));          // +1 self loop
    fdis[t] = dd;
    int node = (b << 8) + t;
    if (node < N)
        meta[node] = make_int2((o << 7) | (pv >> 4), __float_as_int(dd));
    __syncthreads();
    for (int e = base + t; e < base + ecnt; e += TPB) {
        int p = pairs[e];
        int pos = atomicAdd(&cur[p & 255], 1);
        csr[pos] = p >> 8;
    }
    // pad this node's run with the zero-row index N (disjoint addresses)
    for (int e = o + dv; e < o + pv; ++e) csr[e] = N;

    // z0 conversion: 16 passes, 16 nodes each, coalesced float4 reads.
    int ni = t >> 4, c = t & 15;
    for (int p = 0; p < 16; ++p) {
        int nd = (b << 8) + p * 16 + ni;
        if (nd < N) {
            float dvv = fdis[p * 16 + ni];
            float4 h = ((const float4*)x)[nd * 16 + c];
            float4 r = {h.x * dvv, h.y * dvv, h.z * dvv, h.w * dvv};
            z0[nd * 16 + c] = f4_to_h4(r);
        }
    }
    if (b == 0 && t < 16) z0[(size_t)N * 16 + t] = make_ushort4(0, 0, 0, 0);
}

// Cooperative gather (fp16 rows, PADDED csr): 16 lanes batch-load 16 CSR
// indices in one coalesced read, broadcast via __shfl, then issue 16
// INDEPENDENT 8B row-chunk loads. No remainder tail (padding).
__device__ __forceinline__ float4 gather_rows(const ushort4* __restrict__ y4,
                                              const int* __restrict__ csr,
                                              int start, int nbatch, int c,
                                              float4 acc) {
    const int base = threadIdx.x & 48;           // group base lane within wave
    for (int bt = 0; bt < nbatch; ++bt) {
        int idx = csr[start + bt * 16 + c];
        #pragma unroll
        for (int k = 0; k < 16; ++k) {
            int s = __shfl(idx, base + k);
            float4 v = h4_to_f4(y4[s * 16 + c]);
            acc.x += v.x; acc.y += v.y; acc.z += v.z; acc.w += v.w;
        }
    }
    return acc;
}

// Shfl-based mm: s (cols 4c..4c+3 of node ni) is distributed across the 16
// lanes of the group; broadcast via __shfl instead of an LDS hs round-trip.
// u += s_row @ W, where lane c accumulates output cols 4c..4c+3.
__device__ __forceinline__ float4 shfl_mm(float4 s, const float4* Ws4, int c) {
    const int base = threadIdx.x & 48;
    float4 u = {0.f, 0.f, 0.f, 0.f};
    #pragma unroll
    for (int r = 0; r < 4; ++r) {
        float sr = (r == 0) ? s.x : (r == 1) ? s.y : (r == 2) ? s.z : s.w;
        #pragma unroll
        for (int q = 0; q < 16; ++q) {
            float hv = __shfl(sr, base + q);     // s[node][q*4+r]
            float4 w = Ws4[(q * 4 + r) * 16 + c];
            u.x = fmaf(hv, w.x, u.x);
            u.y = fmaf(hv, w.y, u.y);
            u.z = fmaf(hv, w.z, u.z);
            u.w = fmaf(hv, w.w, u.w);
        }
    }
    return u;
}

// ---------------------------------------------------------------------------
// Layer: s = z_v + Agg z_u (gather); u = s @ W; zout = fp16(dis*relu(dis*u+b)).
// 16 nodes/block, 16 threads/node. Only W in LDS (16 KB).
// ---------------------------------------------------------------------------
__global__ __launch_bounds__(TPB) void layer_mm(const ushort4* __restrict__ z,
                                                const int* __restrict__ csr,
                                                const int2* __restrict__ meta,
                                                const float* __restrict__ b,
                                                const float* __restrict__ W,
                                                ushort4* __restrict__ zout, int n) {
    __shared__ float Ws[64 * 64];
    int t = threadIdx.x;
    float4* Ws4 = (float4*)Ws;
    const float4* W4g = (const float4*)W;
    #pragma unroll
    for (int i = 0; i < 4; ++i) Ws4[t + i * TPB] = W4g[t + i * TPB];

    if (blockIdx.x == 0 && t < 16)               // zero row N for next layer
        zout[(size_t)n * 16 + t] = make_ushort4(0, 0, 0, 0);

    int ni = t >> 4, c = t & 15;
    int node = blockIdx.x * 16 + ni;
    float4 s = {0.f, 0.f, 0.f, 0.f};
    float dv = 0.f;
    if (node < n) {
        int2 m = meta[node];
        int start = ((unsigned)m.x) >> 7;
        int nbatch = m.x & 127;
        dv = __int_as_float(m.y);
        s = h4_to_f4(z[node * 16 + c]);          // self-loop term z_v
        s = gather_rows(z, csr, start, nbatch, c, s);
    }
    __syncthreads();                             // Ws fully staged
    float4 u = shfl_mm(s, Ws4, c);
    if (node < n) {
        float4 bb = ((const float4*)b)[c];
        float4 r;
        r.x = fmaxf(fmaf(dv, u.x, bb.x), 0.f) * dv;
        r.y = fmaxf(fmaf(dv, u.y, bb.y), 0.f) * dv;
        r.z = fmaxf(fmaf(dv, u.z, bb.z), 0.f) * dv;
        r.w = fmaxf(fmaf(dv, u.w, bb.w), 0.f) * dv;
        zout[node * 16 + c] = f4_to_h4(r);       // z_{l+1} = dis*relu(...)
    }
}

// ---------------------------------------------------------------------------
// Final: s = gather(z2); h = relu(dis*(s@W2)+b2); out = h @ linW + linb.
// Both mms via shfl broadcast (no hs buffer).
// ---------------------------------------------------------------------------
__global__ __launch_bounds__(TPB) void layer_final(const ushort4* __restrict__ z,
                                                   const int* __restrict__ csr,
                                                   const int2* __restrict__ meta,
                                                   const float* __restrict__ b,
                                                   const float* __restrict__ W,
                                                   const float* __restrict__ Wl,
                                                   const float* __restrict__ bl,
                                                   float* __restrict__ out, int n) {
    __shared__ float Ws[64 * 64];
    __shared__ float Wls[64 * 8];
    __shared__ float bls[8];
    int t = threadIdx.x;
    float4* Ws4 = (float4*)Ws;
    const float4* W4g = (const float4*)W;
    #pragma unroll
    for (int i = 0; i < 4; ++i) Ws4[t + i * TPB] = W4g[t + i * TPB];
    if (t < 128) ((float4*)Wls)[t] = ((const float4*)Wl)[t];
    if (t < 8) bls[t] = bl[t];

    int ni = t >> 4, c = t & 15;
    int node = blockIdx.x * 16 + ni;
    float4 s = {0.f, 0.f, 0.f, 0.f};
    float dv = 0.f;
    if (node < n) {
        int2 m = meta[node];
        int start = ((unsigned)m.x) >> 7;
        int nbatch = m.x & 127;
        dv = __int_as_float(m.y);
        s = h4_to_f4(z[node * 16 + c]);
        s = gather_rows(z, csr, start, nbatch, c, s);
    }
    __syncthreads();                             // Ws/Wls/bls staged
    float4 u = shfl_mm(s, Ws4, c);
    float4 bb = ((const float4*)b)[c];
    float4 h;
    h.x = fmaxf(fmaf(dv, u.x, bb.x), 0.f);
    h.y = fmaxf(fmaf(dv, u.y, bb.y), 0.f);
    h.z = fmaxf(fmaf(dv, u.z, bb.z), 0.f);
    h.w = fmaxf(fmaf(dv, u.w, bb.w), 0.f);

    // second mm (64 -> 8) via shfl: lane c<8 computes output col c.
    const int base = threadIdx.x & 48;
    int col = c & 7;
    float acc = bls[col];
    #pragma unroll
    for (int r = 0; r < 4; ++r) {
        float hr = (r == 0) ? h.x : (r == 1) ? h.y : (r == 2) ? h.z : h.w;
        #pragma unroll
        for (int q = 0; q < 16; ++q) {
            float hv = __shfl(hr, base + q);
            acc = fmaf(hv, Wls[(q * 4 + r) * 8 + col], acc);
        }
    }
    if (c < 8 && node < n) out[node * 8 + col] = acc;
}

extern "C" void kernel_launch(void* const* d_in, const int* in_sizes, int n_in,
                              void* d_out, int out_size, void* d_ws, size_t ws_size,
                              hipStream_t stream) {
    const float* x  = (const float*)d_in[0];
    const void*  ei = d_in[1];
    const float* W0 = (const float*)d_in[2];
    const float* b0 = (const float*)d_in[3];
    const float* W1 = (const float*)d_in[4];
    const float* b1 = (const float*)d_in[5];
    const float* W2 = (const float*)d_in[6];
    const float* b2 = (const float*)d_in[7];
    const float* Wl = (const float*)d_in[8];
    const float* bl = (const float*)d_in[9];

    const long long E = in_sizes[1] / 2;                 // 800000
    const int dh = in_sizes[3];                          // 64
    const int din = in_sizes[2] / dh;                    // 64
    const int N = in_sizes[0] / din;                     // 50000
    const int nb = (N + 255) >> 8;                       // 196 buckets

    // Workspace carve (256-aligned): ~39 MB total
    char* ws = (char*)d_ws;
    size_t off = 0;
    auto alloc = [&](size_t bytes) -> char* {
        char* r = ws + off;
        off += (bytes + 255) & ~(size_t)255;
        return r;
    };
    int*     gcur    = (int*)    alloc(1024);
    int2*    meta    = (int2*)   alloc((size_t)N * 8);
    int*     pairs   = (int*)    alloc((size_t)nb * CAP * 4);     // 12.8 MB
    int*     csr     = (int*)    alloc((size_t)nb * CAP * 4);     // 12.8 MB
    ushort4* zbA     = (ushort4*)alloc((size_t)(N + 1) * 64 * 2); // fp16 rows (+zero row)
    ushort4* zbB     = (ushort4*)alloc((size_t)(N + 1) * 64 * 2);

    // --- preprocessing ---
    hipMemsetAsync(gcur, 0, 256 * sizeof(int), stream);
    p3_scatter<<<256, TPB, 0, stream>>>(ei, E, gcur, pairs);
    p4_fill<<<nb, TPB, 0, stream>>>(pairs, gcur, x, meta, csr, zbA, N);

    // --- 3 layers: gather -> mm -> relu ---
    const int gL = (N + 15) / 16;                        // 3125
    layer_mm<<<gL, TPB, 0, stream>>>(zbA, csr, meta, b0, W0, zbB, N);
    layer_mm<<<gL, TPB, 0, stream>>>(zbB, csr, meta, b1, W1, zbA, N);
    layer_final<<<gL, TPB, 0, stream>>>(zbA, csr, meta, b2, W2, Wl, bl,
                                        (float*)d_out, N);
}